// Round 1
// baseline (317.082 us; speedup 1.0000x reference)
//
#include <hip/hip_runtime.h>

// 2-layer tanh RNN, T=2048, B=2048, EMB=10, HID=8, NCLS=4, VOCAB=4.
// Time-chunking with 256-step warm-up (measured contraction rho^256 ~ 4e-3).
//
// R4 change (from R3 post-mortem: 1 wave/SIMD, VALUBusy ~55%, ~45% of issue
// slots idle = trans-pipe occupancy + dependency stalls the single wave
// cannot overlap):
//  - NCHUNK 32 -> 64 (CHUNK 64 -> 32): 2048 waves = 2 waves/SIMD machine-wide.
//    Per-SIMD step count rises 320 -> 2x288 (warm-up redundancy 5x -> 9x),
//    but the second wave fills the idle issue slots (VALU and trans issue
//    from different waves co-schedule, m114-style). Net predicted ~0.8x.
//  - __launch_bounds__(64, 2) to force <=256 unified VGPR/wave so both
//    waves are actually resident per SIMD (R3 live-set ~250, fits).

#define T_LEN 2048
#define B_LEN 2048
#define EMB_D 10
#define NCHUNK 64
#define CHUNK (T_LEN / NCHUNK)   // 32
#define WARM 256
#define KSCALE 2.8853900817779268f   // 2*log2(e)

typedef float v2f __attribute__((ext_vector_type(2)));

#define PINV(v) asm volatile("" : "+v"(v))
#define PINS(v) asm volatile("" : "+s"(v))

// pre is already scaled by 2*log2(e): tanh = 1 - 2/(2^pre + 1)
__device__ __forceinline__ float tanh_scaled(float pre) {
    float e = __builtin_amdgcn_exp2f(pre);
    float r = __builtin_amdgcn_rcpf(e + 1.0f);
    return __builtin_fmaf(-2.0f, r, 1.0f);
}

__device__ __forceinline__ v2f fma2(v2f a, v2f b, v2f c) {
    return __builtin_elementwise_fma(a, b, c);
}

__global__ void __launch_bounds__(64, 2)
rnn_fused(const int* __restrict__ x,
          const float* __restrict__ emb,
          const float* __restrict__ Wih0,
          const float* __restrict__ Whh0,
          const float* __restrict__ bih0,
          const float* __restrict__ bhh0,
          const float* __restrict__ Wih1,
          const float* __restrict__ Whh1,
          const float* __restrict__ bih1,
          const float* __restrict__ bhh1,
          const float* __restrict__ Wfc,
          const float* __restrict__ bfc,
          float* __restrict__ out)
{
    __shared__ __align__(16) float P[4][8];   // k-scaled pre-activation table, layer 0
    const int lane = threadIdx.x;
    if (lane < 32) {
        const int v = lane >> 3, l = lane & 7;
        float s = bih0[l] + bhh0[l];
        #pragma unroll
        for (int d = 0; d < EMB_D; ++d) s += Wih0[l * EMB_D + d] * emb[v * EMB_D + d];
        P[v][l] = s * KSCALE;
    }

    // Packed weights: wpk[p*8+j] = (W[2p][j], W[2p+1][j]) * KSCALE. Pinned in VGPRs.
    v2f whh0pk[32], wih1pk[32], whh1pk[32], b1pk[4];
    #pragma unroll
    for (int p = 0; p < 4; ++p)
        #pragma unroll
        for (int j = 0; j < 8; ++j) {
            v2f w;
            w.x = Whh0[(2 * p) * 8 + j] * KSCALE;
            w.y = Whh0[(2 * p + 1) * 8 + j] * KSCALE;
            PINV(w); whh0pk[p * 8 + j] = w;
        }
    #pragma unroll
    for (int p = 0; p < 4; ++p)
        #pragma unroll
        for (int j = 0; j < 8; ++j) {
            v2f w;
            w.x = Wih1[(2 * p) * 8 + j] * KSCALE;
            w.y = Wih1[(2 * p + 1) * 8 + j] * KSCALE;
            PINV(w); wih1pk[p * 8 + j] = w;
        }
    #pragma unroll
    for (int p = 0; p < 4; ++p)
        #pragma unroll
        for (int j = 0; j < 8; ++j) {
            v2f w;
            w.x = Whh1[(2 * p) * 8 + j] * KSCALE;
            w.y = Whh1[(2 * p + 1) * 8 + j] * KSCALE;
            PINV(w); whh1pk[p * 8 + j] = w;
        }
    #pragma unroll
    for (int p = 0; p < 4; ++p) {
        v2f w;
        w.x = (bih1[2 * p]     + bhh1[2 * p])     * KSCALE;
        w.y = (bih1[2 * p + 1] + bhh1[2 * p + 1]) * KSCALE;
        PINV(w); b1pk[p] = w;
    }

    // FC weights in SGPRs (wave-uniform; v_fma_f32 takes 1 SGPR operand).
    float wfc[32], bf[4];
    #pragma unroll
    for (int i = 0; i < 32; ++i) { wfc[i] = Wfc[i]; PINS(wfc[i]); }
    #pragma unroll
    for (int i = 0; i < 4; ++i)  { bf[i] = bfc[i]; PINS(bf[i]); }

    __syncthreads();

    const int tid = blockIdx.x * 64 + lane;
    const int b = tid & (B_LEN - 1);     // consecutive lanes -> consecutive b (coalesced)
    const int chunk = tid >> 11;         // uniform within a wave, 0..63
    const int t_begin = chunk * CHUNK;
    const int t_end = t_begin + CHUNK;
    int t_start = t_begin - WARM;
    if (t_start < 0) t_start = 0;        // early chunks: exact initial state

    float h0[8], h1[8];
    #pragma unroll
    for (int i = 0; i < 8; ++i) { h0[i] = 0.f; h1[i] = 0.f; }

    // Software pipeline: x prefetched 2 steps ahead, P lookup 1 step ahead.
    const v2f* __restrict__ Ppk = (const v2f*)&P[0][0];   // Ppk[v*4 + p]
    int xn = x[t_start * B_LEN + b];
    v2f pq[4];
    #pragma unroll
    for (int p = 0; p < 4; ++p) pq[p] = Ppk[xn * 4 + p];
    int x1 = x[(t_start + 1) * B_LEN + b];

    float4* __restrict__ outv = (float4*)out;
    const int tmax = t_end - 1;

    // ---- warm-up loop (no FC, no store) ----
    for (int t = t_start; t < t_begin; ++t) {
        int x2 = x[(t + 2) * B_LEN + b];
        v2f nq[4];
        #pragma unroll
        for (int p = 0; p < 4; ++p) nq[p] = Ppk[x1 * 4 + p];

        // Layer 0: acc = P[x_t] + Whh0 @ h0 (packed over output pairs)
        v2f acc[4];
        #pragma unroll
        for (int p = 0; p < 4; ++p) acc[p] = pq[p];
        #pragma unroll
        for (int j = 0; j < 8; ++j) {
            v2f hb = {h0[j], h0[j]};
            #pragma unroll
            for (int p = 0; p < 4; ++p) acc[p] = fma2(whh0pk[p * 8 + j], hb, acc[p]);
        }
        #pragma unroll
        for (int p = 0; p < 4; ++p) {
            h0[2 * p]     = tanh_scaled(acc[p].x);
            h0[2 * p + 1] = tanh_scaled(acc[p].y);
        }

        // Layer 1: acc1 = b1 + Wih1 @ h0 + Whh1 @ h1
        v2f acc1[4];
        #pragma unroll
        for (int p = 0; p < 4; ++p) acc1[p] = b1pk[p];
        #pragma unroll
        for (int j = 0; j < 8; ++j) {
            v2f hb = {h0[j], h0[j]};
            #pragma unroll
            for (int p = 0; p < 4; ++p) acc1[p] = fma2(wih1pk[p * 8 + j], hb, acc1[p]);
        }
        #pragma unroll
        for (int j = 0; j < 8; ++j) {
            v2f hb = {h1[j], h1[j]};
            #pragma unroll
            for (int p = 0; p < 4; ++p) acc1[p] = fma2(whh1pk[p * 8 + j], hb, acc1[p]);
        }
        #pragma unroll
        for (int p = 0; p < 4; ++p) {
            h1[2 * p]     = tanh_scaled(acc1[p].x);
            h1[2 * p + 1] = tanh_scaled(acc1[p].y);
        }

        #pragma unroll
        for (int p = 0; p < 4; ++p) pq[p] = nq[p];
        x1 = x2;
    }

    // ---- output loop (FC + coalesced float4 store) ----
    for (int t = t_begin; t < t_end; ++t) {
        int tp = t + 2; if (tp > tmax) tp = tmax;
        int x2 = x[tp * B_LEN + b];
        v2f nq[4];
        #pragma unroll
        for (int p = 0; p < 4; ++p) nq[p] = Ppk[x1 * 4 + p];

        v2f acc[4];
        #pragma unroll
        for (int p = 0; p < 4; ++p) acc[p] = pq[p];
        #pragma unroll
        for (int j = 0; j < 8; ++j) {
            v2f hb = {h0[j], h0[j]};
            #pragma unroll
            for (int p = 0; p < 4; ++p) acc[p] = fma2(whh0pk[p * 8 + j], hb, acc[p]);
        }
        #pragma unroll
        for (int p = 0; p < 4; ++p) {
            h0[2 * p]     = tanh_scaled(acc[p].x);
            h0[2 * p + 1] = tanh_scaled(acc[p].y);
        }

        v2f acc1[4];
        #pragma unroll
        for (int p = 0; p < 4; ++p) acc1[p] = b1pk[p];
        #pragma unroll
        for (int j = 0; j < 8; ++j) {
            v2f hb = {h0[j], h0[j]};
            #pragma unroll
            for (int p = 0; p < 4; ++p) acc1[p] = fma2(wih1pk[p * 8 + j], hb, acc1[p]);
        }
        #pragma unroll
        for (int j = 0; j < 8; ++j) {
            v2f hb = {h1[j], h1[j]};
            #pragma unroll
            for (int p = 0; p < 4; ++p) acc1[p] = fma2(whh1pk[p * 8 + j], hb, acc1[p]);
        }
        #pragma unroll
        for (int p = 0; p < 4; ++p) {
            h1[2 * p]     = tanh_scaled(acc1[p].x);
            h1[2 * p + 1] = tanh_scaled(acc1[p].y);
        }

        // FC epilogue: scalar v_fma with SGPR weight operand.
        float s0 = bf[0], s1 = bf[1], s2 = bf[2], s3 = bf[3];
        #pragma unroll
        for (int j = 0; j < 8; ++j) {
            s0 = __builtin_fmaf(wfc[0 * 8 + j], h1[j], s0);
            s1 = __builtin_fmaf(wfc[1 * 8 + j], h1[j], s1);
            s2 = __builtin_fmaf(wfc[2 * 8 + j], h1[j], s2);
            s3 = __builtin_fmaf(wfc[3 * 8 + j], h1[j], s3);
        }
        float4 o; o.x = s0; o.y = s1; o.z = s2; o.w = s3;
        outv[t * B_LEN + b] = o;   // 16B/lane, fully coalesced

        #pragma unroll
        for (int p = 0; p < 4; ++p) pq[p] = nq[p];
        x1 = x2;
    }
}

extern "C" void kernel_launch(void* const* d_in, const int* in_sizes, int n_in,
                              void* d_out, int out_size, void* d_ws, size_t ws_size,
                              hipStream_t stream) {
    const int*   x    = (const int*)d_in[0];
    const float* emb  = (const float*)d_in[1];
    const float* Wih0 = (const float*)d_in[2];
    const float* Whh0 = (const float*)d_in[3];
    const float* bih0 = (const float*)d_in[4];
    const float* bhh0 = (const float*)d_in[5];
    const float* Wih1 = (const float*)d_in[6];
    const float* Whh1 = (const float*)d_in[7];
    const float* bih1 = (const float*)d_in[8];
    const float* bhh1 = (const float*)d_in[9];
    const float* Wfc  = (const float*)d_in[10];
    const float* bfc  = (const float*)d_in[11];
    float* out = (float*)d_out;

    dim3 grid((B_LEN / 64) * NCHUNK);   // 2048 blocks x 64 threads = 2 waves/SIMD
    dim3 block(64);
    hipLaunchKernelGGL(rnn_fused, grid, block, 0, stream,
                       x, emb, Wih0, Whh0, bih0, bhh0,
                       Wih1, Whh1, bih1, bhh1, Wfc, bfc, out);
}

// Round 2
// 239.609 us; speedup vs baseline: 1.3233x; 1.3233x over previous
//
#include <hip/hip_runtime.h>

// 2-layer tanh RNN, T=2048, B=2048, EMB=10, HID=8, NCLS=4, VOCAB=4.
// Time-chunking with 256-step warm-up (measured contraction rho^256 ~ 4e-3).
//
// R5 changes (from R4 post-mortem: 2 waves/SIMD filled idle slots, 1460->1200
// cy/step, but 1.8x warm-up redundancy swamped it -> net 1.48x SLOWER.
// Total work = T + NCHUNK*WARM makes chunk-occupancy a dead lever):
//  1. Revert to NCHUNK=32, 1 wave/SIMD, __launch_bounds__(64,1).
//  2. LAYER SKEW: iteration t computes L1(t) and L0(t+1) -- mutually
//     independent (both read only h0(t), h1(t-1)). Two half-length dep
//     chains interleave in one wave instead of one serial L0->tanh->L1->tanh
//     chain. Critical path ~160cy -> ~90cy/step; kernel becomes issue-bound.
//  3. Packed h state (v2f h0p/h1p) with .xx/.yy broadcast swizzles so clang
//     can fold broadcasts into v_pk_fma_f32 op_sel (removes ~48 movs/step;
//     no-regression fallback: same movs as before).

#define T_LEN 2048
#define B_LEN 2048
#define EMB_D 10
#define NCHUNK 32
#define CHUNK (T_LEN / NCHUNK)   // 64
#define WARM 256
#define KSCALE 2.8853900817779268f   // 2*log2(e)

typedef float v2f __attribute__((ext_vector_type(2)));

#define PINV(v) asm volatile("" : "+v"(v))
#define PINS(v) asm volatile("" : "+s"(v))

// pre is already scaled by 2*log2(e): tanh = 1 - 2/(2^pre + 1)
__device__ __forceinline__ float tanh_scaled(float pre) {
    float e = __builtin_amdgcn_exp2f(pre);
    float r = __builtin_amdgcn_rcpf(e + 1.0f);
    return __builtin_fmaf(-2.0f, r, 1.0f);
}

__device__ __forceinline__ v2f fma2(v2f a, v2f b, v2f c) {
    return __builtin_elementwise_fma(a, b, c);
}

__global__ void __launch_bounds__(64, 1)
rnn_fused(const int* __restrict__ x,
          const float* __restrict__ emb,
          const float* __restrict__ Wih0,
          const float* __restrict__ Whh0,
          const float* __restrict__ bih0,
          const float* __restrict__ bhh0,
          const float* __restrict__ Wih1,
          const float* __restrict__ Whh1,
          const float* __restrict__ bih1,
          const float* __restrict__ bhh1,
          const float* __restrict__ Wfc,
          const float* __restrict__ bfc,
          float* __restrict__ out)
{
    __shared__ __align__(16) float P[4][8];   // k-scaled pre-activation table, layer 0
    const int lane = threadIdx.x;
    if (lane < 32) {
        const int v = lane >> 3, l = lane & 7;
        float s = bih0[l] + bhh0[l];
        #pragma unroll
        for (int d = 0; d < EMB_D; ++d) s += Wih0[l * EMB_D + d] * emb[v * EMB_D + d];
        P[v][l] = s * KSCALE;
    }

    // Packed weights: wpk[p*8+j] = (W[2p][j], W[2p+1][j]) * KSCALE. Pinned in VGPRs.
    v2f whh0pk[32], wih1pk[32], whh1pk[32], b1pk[4];
    #pragma unroll
    for (int p = 0; p < 4; ++p)
        #pragma unroll
        for (int j = 0; j < 8; ++j) {
            v2f w;
            w.x = Whh0[(2 * p) * 8 + j] * KSCALE;
            w.y = Whh0[(2 * p + 1) * 8 + j] * KSCALE;
            PINV(w); whh0pk[p * 8 + j] = w;
        }
    #pragma unroll
    for (int p = 0; p < 4; ++p)
        #pragma unroll
        for (int j = 0; j < 8; ++j) {
            v2f w;
            w.x = Wih1[(2 * p) * 8 + j] * KSCALE;
            w.y = Wih1[(2 * p + 1) * 8 + j] * KSCALE;
            PINV(w); wih1pk[p * 8 + j] = w;
        }
    #pragma unroll
    for (int p = 0; p < 4; ++p)
        #pragma unroll
        for (int j = 0; j < 8; ++j) {
            v2f w;
            w.x = Whh1[(2 * p) * 8 + j] * KSCALE;
            w.y = Whh1[(2 * p + 1) * 8 + j] * KSCALE;
            PINV(w); whh1pk[p * 8 + j] = w;
        }
    #pragma unroll
    for (int p = 0; p < 4; ++p) {
        v2f w;
        w.x = (bih1[2 * p]     + bhh1[2 * p])     * KSCALE;
        w.y = (bih1[2 * p + 1] + bhh1[2 * p + 1]) * KSCALE;
        PINV(w); b1pk[p] = w;
    }

    // FC weights in SGPRs (wave-uniform; v_fma_f32 takes 1 SGPR operand).
    float wfc[32], bf[4];
    #pragma unroll
    for (int i = 0; i < 32; ++i) { wfc[i] = Wfc[i]; PINS(wfc[i]); }
    #pragma unroll
    for (int i = 0; i < 4; ++i)  { bf[i] = bfc[i]; PINS(bf[i]); }

    __syncthreads();

    const int tid = blockIdx.x * 64 + lane;
    const int b = tid & (B_LEN - 1);     // consecutive lanes -> consecutive b (coalesced)
    const int chunk = tid >> 11;         // uniform within a wave, 0..31
    const int t_begin = chunk * CHUNK;
    const int t_end = t_begin + CHUNK;
    int t_start = t_begin - WARM;
    if (t_start < 0) t_start = 0;        // chunk 0: exact initial state

    const v2f* __restrict__ Ppk = (const v2f*)&P[0][0];   // Ppk[v*4 + p]
    float4* __restrict__ outv = (float4*)out;
    const int tmax = t_end - 1;

    // Packed state: h0p[p] = (h0[2p], h0[2p+1]).
    v2f h0p[4], h1p[4];
    #pragma unroll
    for (int p = 0; p < 4; ++p) { h0p[p] = (v2f){0.f, 0.f}; h1p[p] = (v2f){0.f, 0.f}; }

    // ---- prologue: L0(t_start) with h0_prev = 0  ->  h0 = tanh(P[x_ts]) ----
    {
        int xa = x[t_start * B_LEN + b];
        #pragma unroll
        for (int p = 0; p < 4; ++p) {
            v2f a = Ppk[xa * 4 + p];
            v2f tv; tv.x = tanh_scaled(a.x); tv.y = tanh_scaled(a.y);
            h0p[p] = tv;
        }
    }
    int xb = x[(t_start + 1) * B_LEN + b];
    v2f pq[4];                               // pq = P[x_{t+1}] at loop entry
    #pragma unroll
    for (int p = 0; p < 4; ++p) pq[p] = Ppk[xb * 4 + p];
    int xc = x[(t_start + 2) * B_LEN + b];   // x_{t+2} at loop entry

    // ---- warm-up loop: iteration t computes L1(t), L0(t+1); no FC/store ----
    for (int t = t_start; t < t_begin; ++t) {
        int xl = x[(t + 3) * B_LEN + b];     // t+3 <= t_begin+2 <= 2046, in-bounds
        v2f nq[4];
        #pragma unroll
        for (int p = 0; p < 4; ++p) nq[p] = Ppk[xc * 4 + p];

        // L1(t): acc1 = b1 + Wih1 @ h0(t) + Whh1 @ h1(t-1)
        v2f acc1[4];
        #pragma unroll
        for (int p = 0; p < 4; ++p) acc1[p] = b1pk[p];
        #pragma unroll
        for (int q = 0; q < 4; ++q) {
            v2f hlo = h0p[q].xx, hhi = h0p[q].yy;
            #pragma unroll
            for (int p = 0; p < 4; ++p) acc1[p] = fma2(wih1pk[p * 8 + 2 * q],     hlo, acc1[p]);
            #pragma unroll
            for (int p = 0; p < 4; ++p) acc1[p] = fma2(wih1pk[p * 8 + 2 * q + 1], hhi, acc1[p]);
        }
        #pragma unroll
        for (int q = 0; q < 4; ++q) {
            v2f glo = h1p[q].xx, ghi = h1p[q].yy;
            #pragma unroll
            for (int p = 0; p < 4; ++p) acc1[p] = fma2(whh1pk[p * 8 + 2 * q],     glo, acc1[p]);
            #pragma unroll
            for (int p = 0; p < 4; ++p) acc1[p] = fma2(whh1pk[p * 8 + 2 * q + 1], ghi, acc1[p]);
        }

        // L0(t+1): acc0 = P[x_{t+1}] + Whh0 @ h0(t)   (independent of L1 above)
        v2f acc0[4];
        #pragma unroll
        for (int p = 0; p < 4; ++p) acc0[p] = pq[p];
        #pragma unroll
        for (int q = 0; q < 4; ++q) {
            v2f hlo = h0p[q].xx, hhi = h0p[q].yy;
            #pragma unroll
            for (int p = 0; p < 4; ++p) acc0[p] = fma2(whh0pk[p * 8 + 2 * q],     hlo, acc0[p]);
            #pragma unroll
            for (int p = 0; p < 4; ++p) acc0[p] = fma2(whh0pk[p * 8 + 2 * q + 1], hhi, acc0[p]);
        }

        #pragma unroll
        for (int p = 0; p < 4; ++p) {
            v2f t1; t1.x = tanh_scaled(acc1[p].x); t1.y = tanh_scaled(acc1[p].y);
            h1p[p] = t1;
        }
        #pragma unroll
        for (int p = 0; p < 4; ++p) {
            v2f t0; t0.x = tanh_scaled(acc0[p].x); t0.y = tanh_scaled(acc0[p].y);
            h0p[p] = t0;
        }

        #pragma unroll
        for (int p = 0; p < 4; ++p) pq[p] = nq[p];
        xc = xl;
    }

    // ---- output loop: L1(t) + FC(t) + store; L0(t+1) ----
    for (int t = t_begin; t < t_end; ++t) {
        int tp = t + 3; if (tp > tmax) tp = tmax;
        int xl = x[tp * B_LEN + b];
        v2f nq[4];
        #pragma unroll
        for (int p = 0; p < 4; ++p) nq[p] = Ppk[xc * 4 + p];

        // L1(t)
        v2f acc1[4];
        #pragma unroll
        for (int p = 0; p < 4; ++p) acc1[p] = b1pk[p];
        #pragma unroll
        for (int q = 0; q < 4; ++q) {
            v2f hlo = h0p[q].xx, hhi = h0p[q].yy;
            #pragma unroll
            for (int p = 0; p < 4; ++p) acc1[p] = fma2(wih1pk[p * 8 + 2 * q],     hlo, acc1[p]);
            #pragma unroll
            for (int p = 0; p < 4; ++p) acc1[p] = fma2(wih1pk[p * 8 + 2 * q + 1], hhi, acc1[p]);
        }
        #pragma unroll
        for (int q = 0; q < 4; ++q) {
            v2f glo = h1p[q].xx, ghi = h1p[q].yy;
            #pragma unroll
            for (int p = 0; p < 4; ++p) acc1[p] = fma2(whh1pk[p * 8 + 2 * q],     glo, acc1[p]);
            #pragma unroll
            for (int p = 0; p < 4; ++p) acc1[p] = fma2(whh1pk[p * 8 + 2 * q + 1], ghi, acc1[p]);
        }

        // L0(t+1)  (independent of L1 above; interleaves with it)
        v2f acc0[4];
        #pragma unroll
        for (int p = 0; p < 4; ++p) acc0[p] = pq[p];
        #pragma unroll
        for (int q = 0; q < 4; ++q) {
            v2f hlo = h0p[q].xx, hhi = h0p[q].yy;
            #pragma unroll
            for (int p = 0; p < 4; ++p) acc0[p] = fma2(whh0pk[p * 8 + 2 * q],     hlo, acc0[p]);
            #pragma unroll
            for (int p = 0; p < 4; ++p) acc0[p] = fma2(whh0pk[p * 8 + 2 * q + 1], hhi, acc0[p]);
        }

        #pragma unroll
        for (int p = 0; p < 4; ++p) {
            v2f t1; t1.x = tanh_scaled(acc1[p].x); t1.y = tanh_scaled(acc1[p].y);
            h1p[p] = t1;
        }
        #pragma unroll
        for (int p = 0; p < 4; ++p) {
            v2f t0; t0.x = tanh_scaled(acc0[p].x); t0.y = tanh_scaled(acc0[p].y);
            h0p[p] = t0;
        }

        // FC epilogue on h1(t): scalar v_fma with SGPR weight operand.
        float s0 = bf[0], s1 = bf[1], s2 = bf[2], s3 = bf[3];
        #pragma unroll
        for (int q = 0; q < 4; ++q) {
            s0 = __builtin_fmaf(wfc[0 * 8 + 2 * q], h1p[q].x, s0);
            s0 = __builtin_fmaf(wfc[0 * 8 + 2 * q + 1], h1p[q].y, s0);
            s1 = __builtin_fmaf(wfc[1 * 8 + 2 * q], h1p[q].x, s1);
            s1 = __builtin_fmaf(wfc[1 * 8 + 2 * q + 1], h1p[q].y, s1);
            s2 = __builtin_fmaf(wfc[2 * 8 + 2 * q], h1p[q].x, s2);
            s2 = __builtin_fmaf(wfc[2 * 8 + 2 * q + 1], h1p[q].y, s2);
            s3 = __builtin_fmaf(wfc[3 * 8 + 2 * q], h1p[q].x, s3);
            s3 = __builtin_fmaf(wfc[3 * 8 + 2 * q + 1], h1p[q].y, s3);
        }
        float4 o; o.x = s0; o.y = s1; o.z = s2; o.w = s3;
        outv[t * B_LEN + b] = o;   // 16B/lane, fully coalesced

        #pragma unroll
        for (int p = 0; p < 4; ++p) pq[p] = nq[p];
        xc = xl;
    }
}

extern "C" void kernel_launch(void* const* d_in, const int* in_sizes, int n_in,
                              void* d_out, int out_size, void* d_ws, size_t ws_size,
                              hipStream_t stream) {
    const int*   x    = (const int*)d_in[0];
    const float* emb  = (const float*)d_in[1];
    const float* Wih0 = (const float*)d_in[2];
    const float* Whh0 = (const float*)d_in[3];
    const float* bih0 = (const float*)d_in[4];
    const float* bhh0 = (const float*)d_in[5];
    const float* Wih1 = (const float*)d_in[6];
    const float* Whh1 = (const float*)d_in[7];
    const float* bih1 = (const float*)d_in[8];
    const float* bhh1 = (const float*)d_in[9];
    const float* Wfc  = (const float*)d_in[10];
    const float* bfc  = (const float*)d_in[11];
    float* out = (float*)d_out;

    dim3 grid((B_LEN / 64) * NCHUNK);   // 1024 blocks x 64 threads = 1 wave/SIMD
    dim3 block(64);
    hipLaunchKernelGGL(rnn_fused, grid, block, 0, stream,
                       x, emb, Wih0, Whh0, bih0, bhh0,
                       Wih1, Whh1, bih1, bhh1, Wfc, bfc, out);
}